// Round 4
// baseline (677.817 us; speedup 1.0000x reference)
//
#include <hip/hip_runtime.h>
#include <hip/hip_bf16.h>

// GCN_85804856639970 — 2-layer GCN + FC head, MI355X.
// N=50000, E=800000, 128->128->64, head 64x64. fp32 in/out, edge_index int32.
//
// R4: CSR gather with bf16 intermediates (halve gather bytes), vectorized
// GEMM staging, 4-deep gather unroll.
//   dinv = rsqrt(in_deg+1)
//   hs = (X@W)*dinv[row]                         (pre-scale fused in GEMM, bf16 out)
//   h  = relu(dinv[i]*(hs[i] + sum_nbr hs) + b)  (gather, fused epilogue)
//   out = h2@fcW + fcb

__device__ __forceinline__ float bf16_lo(unsigned u) {
    return __uint_as_float((u & 0xFFFFu) << 16);
}
__device__ __forceinline__ float bf16_hi(unsigned u) {
    return __uint_as_float(u & 0xFFFF0000u);
}
__device__ __forceinline__ float bf16_one(unsigned short u) {
    return __uint_as_float(((unsigned)u) << 16);
}

// ---------------- CSR build ----------------

__global__ void k_zero_int(int* __restrict__ p, int n) {
    int i = blockIdx.x * blockDim.x + threadIdx.x;
    if (i < n) p[i] = 0;
}

__global__ void k_count(const int* __restrict__ dst, int e, int* __restrict__ degi) {
    int i = blockIdx.x * blockDim.x + threadIdx.x;
    if (i < e) atomicAdd(&degi[dst[i]], 1);
}

__global__ void k_scan1(const int* __restrict__ degi, int* __restrict__ rowptr,
                        int* __restrict__ blocksum, int n) {
    __shared__ int s[256];
    int tid = threadIdx.x;
    int i = blockIdx.x * 256 + tid;
    s[tid] = (i < n) ? degi[i] : 0;
    __syncthreads();
#pragma unroll
    for (int off = 1; off < 256; off <<= 1) {
        int t = (tid >= off) ? s[tid - off] : 0;
        __syncthreads();
        s[tid] += t;
        __syncthreads();
    }
    if (i < n) rowptr[i + 1] = s[tid];
    if (tid == 255) blocksum[blockIdx.x] = s[255];
}

__global__ void k_scan2(int* __restrict__ blocksum, int nb) {
    __shared__ int s[256];
    int tid = threadIdx.x;
    s[tid] = (tid < nb) ? blocksum[tid] : 0;
    __syncthreads();
#pragma unroll
    for (int off = 1; off < 256; off <<= 1) {
        int t = (tid >= off) ? s[tid - off] : 0;
        __syncthreads();
        s[tid] += t;
        __syncthreads();
    }
    if (tid < nb) blocksum[tid] = s[tid];
}

__global__ void k_scan3(int* __restrict__ rowptr, const int* __restrict__ blocksum,
                        const int* __restrict__ degi, int* __restrict__ cursor,
                        float* __restrict__ dinv, int n) {
    int i = blockIdx.x * blockDim.x + threadIdx.x;
    if (i >= n) return;
    int off = (blockIdx.x > 0) ? blocksum[blockIdx.x - 1] : 0;
    int incl = rowptr[i + 1] + off;
    rowptr[i + 1] = incl;
    cursor[i] = incl - degi[i];
    dinv[i] = rsqrtf((float)degi[i] + 1.0f);
    if (i == 0) rowptr[0] = 0;
}

__global__ void k_fill(const int* __restrict__ src, const int* __restrict__ dst, int e,
                       int* __restrict__ cursor, unsigned short* __restrict__ col) {
    int i = blockIdx.x * blockDim.x + threadIdx.x;
    if (i >= e) return;
    int d = dst[i];
    int pos = atomicAdd(&cursor[d], 1);
    col[pos] = (unsigned short)src[i];
}

// ---------------- Tiled GEMM ----------------
// 256 threads, R=16 rows/block. MODE 0: v=acc*dinv[row]; MODE 1: v=acc+bias[j].
// TIN: float or __hip_bfloat16. TOUT: float or __hip_bfloat16.
template <int K, int M, int R, int MODE, typename TIN, typename TOUT>
__global__ void k_gemm(const TIN* __restrict__ X, const float* __restrict__ W,
                       const float* __restrict__ dinv, const float* __restrict__ bias,
                       TOUT* __restrict__ out, int n) {
    constexpr int G = 256 / M;
    constexpr int RT = R / G;
    __shared__ float xs[R * (K + 1)];
    int tid = threadIdx.x;
    int base = blockIdx.x * R;

    if constexpr (sizeof(TIN) == 2) {
        // packed bf16 pairs, 4B/thread
        const unsigned* Xp = (const unsigned*)X;
        for (int idx = tid; idx < R * (K / 2); idx += 256) {
            int r = idx / (K / 2), kp = idx - r * (K / 2);
            int row = base + r;
            unsigned u = (row < n) ? Xp[(size_t)row * (K / 2) + kp] : 0u;
            xs[r * (K + 1) + 2 * kp]     = bf16_lo(u);
            xs[r * (K + 1) + 2 * kp + 1] = bf16_hi(u);
        }
    } else {
        const float4* Xp = (const float4*)X;
        for (int idx = tid; idx < R * (K / 4); idx += 256) {
            int r = idx / (K / 4), kq = idx - r * (K / 4);
            int row = base + r;
            float4 v = (row < n) ? Xp[(size_t)row * (K / 4) + kq]
                                 : make_float4(0.f, 0.f, 0.f, 0.f);
            float* d = &xs[r * (K + 1) + 4 * kq];
            d[0] = v.x; d[1] = v.y; d[2] = v.z; d[3] = v.w;
        }
    }
    __syncthreads();

    int j = tid % M;
    int g = tid / M;
    float acc[RT];
#pragma unroll
    for (int r = 0; r < RT; ++r) acc[r] = 0.0f;

    for (int k = 0; k < K; ++k) {
        float w = W[(size_t)k * M + j];
#pragma unroll
        for (int r = 0; r < RT; ++r)
            acc[r] += xs[(g * RT + r) * (K + 1) + k] * w;
    }

#pragma unroll
    for (int r = 0; r < RT; ++r) {
        int row = base + g * RT + r;
        if (row < n) {
            float v = (MODE == 0) ? acc[r] * dinv[row] : acc[r] + bias[j];
            if constexpr (sizeof(TOUT) == 2)
                out[(size_t)row * M + j] = __float2bfloat16(v);
            else
                out[(size_t)row * M + j] = v;
        }
    }
}

// ---------------- CSR aggregation (wave per node), bf16 hs ----------------
// out[i] = relu(dinv[i]*(hs[i] + sum_{c} hs[c]) + bias)
// M=128: lane holds a bf16 pair (256B/row). M=64: lane holds one bf16 (128B/row).
template <int M, typename TOUT>
__global__ void k_agg(const int* __restrict__ rowptr, const unsigned short* __restrict__ col,
                      const unsigned short* __restrict__ hs, const float* __restrict__ dinv,
                      const float* __restrict__ bias, TOUT* __restrict__ out, int n) {
    int wave = threadIdx.x >> 6;
    int lane = threadIdx.x & 63;
    int node = blockIdx.x * 4 + wave;
    if (node >= n) return;

    int beg = rowptr[node];
    int end = rowptr[node + 1];
    float di = dinv[node];

    if constexpr (M == 128) {
        const unsigned* hp = (const unsigned*)hs;  // row = 64 packed pairs
        unsigned su = hp[(size_t)node * 64 + lane];
        float ax0 = bf16_lo(su), ay0 = bf16_hi(su);
        float ax1 = 0.f, ay1 = 0.f, ax2 = 0.f, ay2 = 0.f, ax3 = 0.f, ay3 = 0.f;
        int i = beg;
        for (; i + 3 < end; i += 4) {
            unsigned u0 = hp[(size_t)col[i]     * 64 + lane];
            unsigned u1 = hp[(size_t)col[i + 1] * 64 + lane];
            unsigned u2 = hp[(size_t)col[i + 2] * 64 + lane];
            unsigned u3 = hp[(size_t)col[i + 3] * 64 + lane];
            ax0 += bf16_lo(u0); ay0 += bf16_hi(u0);
            ax1 += bf16_lo(u1); ay1 += bf16_hi(u1);
            ax2 += bf16_lo(u2); ay2 += bf16_hi(u2);
            ax3 += bf16_lo(u3); ay3 += bf16_hi(u3);
        }
        for (; i < end; ++i) {
            unsigned u0 = hp[(size_t)col[i] * 64 + lane];
            ax0 += bf16_lo(u0); ay0 += bf16_hi(u0);
        }
        float vx = fmaxf(di * ((ax0 + ax1) + (ax2 + ax3)) + bias[2 * lane], 0.0f);
        float vy = fmaxf(di * ((ay0 + ay1) + (ay2 + ay3)) + bias[2 * lane + 1], 0.0f);
        if constexpr (sizeof(TOUT) == 2) {
            __hip_bfloat162 o;
            o.x = __float2bfloat16(vx);
            o.y = __float2bfloat16(vy);
            ((__hip_bfloat162*)out)[(size_t)node * 64 + lane] = o;
        } else {
            ((float2*)out)[(size_t)node * 64 + lane] = make_float2(vx, vy);
        }
    } else {  // M == 64
        float a0 = bf16_one(hs[(size_t)node * 64 + lane]);
        float a1 = 0.f, a2 = 0.f, a3 = 0.f;
        int i = beg;
        for (; i + 3 < end; i += 4) {
            a0 += bf16_one(hs[(size_t)col[i]     * 64 + lane]);
            a1 += bf16_one(hs[(size_t)col[i + 1] * 64 + lane]);
            a2 += bf16_one(hs[(size_t)col[i + 2] * 64 + lane]);
            a3 += bf16_one(hs[(size_t)col[i + 3] * 64 + lane]);
        }
        for (; i < end; ++i) a0 += bf16_one(hs[(size_t)col[i] * 64 + lane]);
        float v = fmaxf(di * ((a0 + a1) + (a2 + a3)) + bias[lane], 0.0f);
        out[(size_t)node * 64 + lane] = (TOUT)v;
    }
}

// ---------------- launch ----------------

extern "C" void kernel_launch(void* const* d_in, const int* in_sizes, int n_in,
                              void* d_out, int out_size, void* d_ws, size_t ws_size,
                              hipStream_t stream) {
    const float* x   = (const float*)d_in[0];
    const int*   ei  = (const int*)d_in[1];
    const float* W1  = (const float*)d_in[2];
    const float* b1  = (const float*)d_in[3];
    const float* W2  = (const float*)d_in[4];
    const float* b2  = (const float*)d_in[5];
    const float* fcW = (const float*)d_in[6];
    const float* fcb = (const float*)d_in[7];
    float* out = (float*)d_out;

    const int N = in_sizes[0] / 128;
    const int E = in_sizes[1] / 2;
    const int* src = ei;
    const int* dst = ei + E;

    // ---- workspace carve (16B-aligned), peak ~47 MB ----
    auto align16 = [](size_t v) { return (v + 15) & ~(size_t)15; };
    char* p = (char*)d_ws;
    int* rowptr = (int*)p;                     p += align16(sizeof(int) * (N + 1));
    unsigned short* col = (unsigned short*)p;  p += align16(sizeof(unsigned short) * E);
    float* dinv = (float*)p;                   p += align16(sizeof(float) * N);
    int* degi = (int*)p;                       p += align16(sizeof(int) * N);
    int* cursor = (int*)p;                     p += align16(sizeof(int) * N);
    int* blocksum = (int*)p;                   p += align16(sizeof(int) * 256);
    unsigned short* hs1 = (unsigned short*)p;  p += align16(2 * (size_t)N * 128);  // bf16
    unsigned short* h1  = (unsigned short*)p;  p += align16(2 * (size_t)N * 128);  // bf16
    unsigned short* hs2 = (unsigned short*)p;  p += align16(2 * (size_t)N * 64);   // bf16
    float* h2 = (float*)p;                     p += align16(sizeof(float) * (size_t)N * 64);

    const int B = 256;
    const int nb = (N + 255) / 256;

    // CSR build
    k_zero_int<<<(N + B - 1) / B, B, 0, stream>>>(degi, N);
    k_count<<<(E + B - 1) / B, B, 0, stream>>>(dst, E, degi);
    k_scan1<<<nb, 256, 0, stream>>>(degi, rowptr, blocksum, N);
    k_scan2<<<1, 256, 0, stream>>>(blocksum, nb);
    k_scan3<<<nb, 256, 0, stream>>>(rowptr, blocksum, degi, cursor, dinv, N);
    k_fill<<<(E + B - 1) / B, B, 0, stream>>>(src, dst, E, cursor, col);

    // Layer 1: 128 -> 128 (fp32 in, bf16 hs1/h1)
    k_gemm<128, 128, 16, 0, float, __hip_bfloat16>
        <<<(N + 15) / 16, 256, 0, stream>>>(x, W1, dinv, nullptr, (__hip_bfloat16*)hs1, N);
    k_agg<128, __hip_bfloat16>
        <<<(N + 3) / 4, 256, 0, stream>>>(rowptr, col, hs1, dinv, b1, (__hip_bfloat16*)h1, N);

    // Layer 2: 128 -> 64 (bf16 in, bf16 hs2; fp32 h2)
    k_gemm<128, 64, 16, 0, __hip_bfloat16, __hip_bfloat16>
        <<<(N + 15) / 16, 256, 0, stream>>>((const __hip_bfloat16*)h1, W2, dinv, nullptr,
                                            (__hip_bfloat16*)hs2, N);
    k_agg<64, float>
        <<<(N + 3) / 4, 256, 0, stream>>>(rowptr, col, hs2, dinv, b2, h2, N);

    // FC head: 64 -> 64 (fp32)
    k_gemm<64, 64, 16, 1, float, float>
        <<<(N + 15) / 16, 256, 0, stream>>>(h2, fcW, nullptr, fcb, out, N);
}

// Round 5
// 293.858 us; speedup vs baseline: 2.3066x; 2.3066x over previous
//
#include <hip/hip_runtime.h>
#include <hip/hip_bf16.h>

// GCN_85804856639970 — 2-layer GCN + FC head, MI355X.
// N=50000, E=800000, 128->128->64, head 64x64. fp32 in/out, edge_index int32.
//
// R5: all GEMMs on MFMA (16x16x32 bf16). Weights pre-transposed to bf16 W^T[n][k]
// so B-frags are contiguous 16B loads; X staged bf16 in padded LDS so A-frags are
// single ds_read_b128. CSR gather aggregation unchanged (bf16 hs, fused epilogue).
//   dinv = rsqrt(in_deg+1)
//   hs = (X@W)*dinv[row]   (MFMA GEMM, pre-scale epilogue, bf16 out)
//   h  = relu(dinv*(hs[i]+sum_nbr hs)+b)  (CSR gather)
//   out = h2@fcW + fcb     (MFMA GEMM, bias epilogue, fp32 out)

typedef __attribute__((ext_vector_type(8))) short bf16x8;
typedef __attribute__((ext_vector_type(4))) float f32x4;

__device__ __forceinline__ unsigned short f2bf(float f) {
    unsigned u = __float_as_uint(f);
    unsigned r = (u + 0x7FFFu + ((u >> 16) & 1u)) >> 16;
    return (unsigned short)r;
}
__device__ __forceinline__ float bf16_lo(unsigned u) {
    return __uint_as_float((u & 0xFFFFu) << 16);
}
__device__ __forceinline__ float bf16_hi(unsigned u) {
    return __uint_as_float(u & 0xFFFF0000u);
}
__device__ __forceinline__ float bf16_one(unsigned short u) {
    return __uint_as_float(((unsigned)u) << 16);
}

// ---------------- CSR build ----------------

__global__ void k_zero_int(int* __restrict__ p, int n) {
    int i = blockIdx.x * blockDim.x + threadIdx.x;
    if (i < n) p[i] = 0;
}

__global__ void k_count(const int* __restrict__ dst, int e, int* __restrict__ degi) {
    int i = blockIdx.x * blockDim.x + threadIdx.x;
    if (i < e) atomicAdd(&degi[dst[i]], 1);
}

__global__ void k_scan1(const int* __restrict__ degi, int* __restrict__ rowptr,
                        int* __restrict__ blocksum, int n) {
    __shared__ int s[256];
    int tid = threadIdx.x;
    int i = blockIdx.x * 256 + tid;
    s[tid] = (i < n) ? degi[i] : 0;
    __syncthreads();
#pragma unroll
    for (int off = 1; off < 256; off <<= 1) {
        int t = (tid >= off) ? s[tid - off] : 0;
        __syncthreads();
        s[tid] += t;
        __syncthreads();
    }
    if (i < n) rowptr[i + 1] = s[tid];
    if (tid == 255) blocksum[blockIdx.x] = s[255];
}

__global__ void k_scan2(int* __restrict__ blocksum, int nb) {
    __shared__ int s[256];
    int tid = threadIdx.x;
    s[tid] = (tid < nb) ? blocksum[tid] : 0;
    __syncthreads();
#pragma unroll
    for (int off = 1; off < 256; off <<= 1) {
        int t = (tid >= off) ? s[tid - off] : 0;
        __syncthreads();
        s[tid] += t;
        __syncthreads();
    }
    if (tid < nb) blocksum[tid] = s[tid];
}

__global__ void k_scan3(int* __restrict__ rowptr, const int* __restrict__ blocksum,
                        const int* __restrict__ degi, int* __restrict__ cursor,
                        float* __restrict__ dinv, int n) {
    int i = blockIdx.x * blockDim.x + threadIdx.x;
    if (i >= n) return;
    int off = (blockIdx.x > 0) ? blocksum[blockIdx.x - 1] : 0;
    int incl = rowptr[i + 1] + off;
    rowptr[i + 1] = incl;
    cursor[i] = incl - degi[i];
    dinv[i] = rsqrtf((float)degi[i] + 1.0f);
    if (i == 0) rowptr[0] = 0;
}

__global__ void k_fill(const int* __restrict__ src, const int* __restrict__ dst, int e,
                       int* __restrict__ cursor, unsigned short* __restrict__ col) {
    int i = blockIdx.x * blockDim.x + threadIdx.x;
    if (i >= e) return;
    int d = dst[i];
    int pos = atomicAdd(&cursor[d], 1);
    col[pos] = (unsigned short)src[i];
}

// ---------------- weight transpose+convert: WT[m][k] = bf16(W[k][m]) ----------------

__global__ void k_wt(const float* __restrict__ W, unsigned short* __restrict__ WT,
                     int K, int M) {
    int i = blockIdx.x * blockDim.x + threadIdx.x;
    if (i >= K * M) return;
    int m = i / K, k = i - m * K;
    WT[i] = f2bf(W[(size_t)k * M + m]);
}

// ---------------- MFMA GEMM ----------------
// C[n x M] = X[n x K] @ W[K x M], W given as WT[M][K] bf16.
// Block: 256 thr = 4 waves; wave owns 16 rows; block covers 64 rows.
// MODE 0: store bf16( acc * dinv[row] ).  MODE 1: store fp32( acc + bias[col] ).
// A-frag (16x16x32): lane holds A[m=lane&15][k=quad*8+j], j=0..7 -> one ds_read_b128.
// C/D: col=lane&15, row=quad*4+reg (verified layout, m89).
template <int K, int M, int MODE, typename TIN>
__global__ __launch_bounds__(256) void k_mgemm(
    const TIN* __restrict__ X, const unsigned short* __restrict__ WT,
    const float* __restrict__ dinv, const float* __restrict__ bias,
    void* __restrict__ outv, int n) {
    constexpr int LDW = K + 8;  // pad: +16B per row, keeps 16B alignment, breaks bank stride
    __shared__ __align__(16) unsigned short xs[64 * LDW];
    int tid = threadIdx.x;
    int base = blockIdx.x * 64;

    if constexpr (sizeof(TIN) == 4) {  // fp32 input -> convert to bf16
        constexpr int C4 = K / 4;
        for (int idx = tid; idx < 64 * C4; idx += 256) {
            int r = idx / C4, c = idx - r * C4;
            int row = base + r;
            float4 v = make_float4(0.f, 0.f, 0.f, 0.f);
            if (row < n) v = ((const float4*)X)[(size_t)row * C4 + c];
            unsigned short* d = &xs[r * LDW + c * 4];
            d[0] = f2bf(v.x); d[1] = f2bf(v.y); d[2] = f2bf(v.z); d[3] = f2bf(v.w);
        }
    } else {  // bf16 input, 16B copies
        constexpr int C8 = K / 8;
        for (int idx = tid; idx < 64 * C8; idx += 256) {
            int r = idx / C8, c = idx - r * C8;
            int row = base + r;
            uint4 v = make_uint4(0u, 0u, 0u, 0u);
            if (row < n) v = ((const uint4*)X)[(size_t)row * C8 + c];
            *(uint4*)&xs[r * LDW + c * 8] = v;
        }
    }
    __syncthreads();

    int wave = tid >> 6, lane = tid & 63;
    int quad = lane >> 4, l16 = lane & 15;
    int rbase = wave * 16;
    constexpr int KB = K / 32;

    bf16x8 afrag[KB];
#pragma unroll
    for (int kb = 0; kb < KB; ++kb)
        afrag[kb] = *(const bf16x8*)&xs[(rbase + l16) * LDW + kb * 32 + quad * 8];

    float dv[4];
#pragma unroll
    for (int r = 0; r < 4; ++r) {
        int row = base + rbase + quad * 4 + r;
        dv[r] = (MODE == 0 && row < n) ? dinv[row] : 0.f;
    }

#pragma unroll
    for (int jt = 0; jt < M / 16; ++jt) {
        f32x4 acc = {0.f, 0.f, 0.f, 0.f};
#pragma unroll
        for (int kb = 0; kb < KB; ++kb) {
            bf16x8 bfrag = *(const bf16x8*)&WT[(size_t)(jt * 16 + l16) * K + kb * 32 + quad * 8];
            acc = __builtin_amdgcn_mfma_f32_16x16x32_bf16(afrag[kb], bfrag, acc, 0, 0, 0);
        }
        int colj = jt * 16 + l16;
        float bv = (MODE == 1) ? bias[colj] : 0.f;
#pragma unroll
        for (int r = 0; r < 4; ++r) {
            int row = base + rbase + quad * 4 + r;
            if (row < n) {
                if constexpr (MODE == 0)
                    ((unsigned short*)outv)[(size_t)row * M + colj] = f2bf(acc[r] * dv[r]);
                else
                    ((float*)outv)[(size_t)row * M + colj] = acc[r] + bv;
            }
        }
    }
}

// ---------------- CSR aggregation (wave per node), bf16 hs ----------------
template <int M, typename TOUT>
__global__ void k_agg(const int* __restrict__ rowptr, const unsigned short* __restrict__ col,
                      const unsigned short* __restrict__ hs, const float* __restrict__ dinv,
                      const float* __restrict__ bias, TOUT* __restrict__ out, int n) {
    int wave = threadIdx.x >> 6;
    int lane = threadIdx.x & 63;
    int node = blockIdx.x * 4 + wave;
    if (node >= n) return;

    int beg = rowptr[node];
    int end = rowptr[node + 1];
    float di = dinv[node];

    if constexpr (M == 128) {
        const unsigned* hp = (const unsigned*)hs;  // row = 64 packed bf16 pairs
        unsigned su = hp[(size_t)node * 64 + lane];
        float ax0 = bf16_lo(su), ay0 = bf16_hi(su);
        float ax1 = 0.f, ay1 = 0.f, ax2 = 0.f, ay2 = 0.f, ax3 = 0.f, ay3 = 0.f;
        int i = beg;
        for (; i + 3 < end; i += 4) {
            unsigned u0 = hp[(size_t)col[i]     * 64 + lane];
            unsigned u1 = hp[(size_t)col[i + 1] * 64 + lane];
            unsigned u2 = hp[(size_t)col[i + 2] * 64 + lane];
            unsigned u3 = hp[(size_t)col[i + 3] * 64 + lane];
            ax0 += bf16_lo(u0); ay0 += bf16_hi(u0);
            ax1 += bf16_lo(u1); ay1 += bf16_hi(u1);
            ax2 += bf16_lo(u2); ay2 += bf16_hi(u2);
            ax3 += bf16_lo(u3); ay3 += bf16_hi(u3);
        }
        for (; i < end; ++i) {
            unsigned u0 = hp[(size_t)col[i] * 64 + lane];
            ax0 += bf16_lo(u0); ay0 += bf16_hi(u0);
        }
        float vx = fmaxf(di * ((ax0 + ax1) + (ax2 + ax3)) + bias[2 * lane], 0.0f);
        float vy = fmaxf(di * ((ay0 + ay1) + (ay2 + ay3)) + bias[2 * lane + 1], 0.0f);
        __hip_bfloat162 o;
        o.x = __float2bfloat16(vx);
        o.y = __float2bfloat16(vy);
        ((__hip_bfloat162*)out)[(size_t)node * 64 + lane] = o;
    } else {  // M == 64
        float a0 = bf16_one(hs[(size_t)node * 64 + lane]);
        float a1 = 0.f, a2 = 0.f, a3 = 0.f;
        int i = beg;
        for (; i + 3 < end; i += 4) {
            a0 += bf16_one(hs[(size_t)col[i]     * 64 + lane]);
            a1 += bf16_one(hs[(size_t)col[i + 1] * 64 + lane]);
            a2 += bf16_one(hs[(size_t)col[i + 2] * 64 + lane]);
            a3 += bf16_one(hs[(size_t)col[i + 3] * 64 + lane]);
        }
        for (; i < end; ++i) a0 += bf16_one(hs[(size_t)col[i] * 64 + lane]);
        float v = fmaxf(di * ((a0 + a1) + (a2 + a3)) + bias[lane], 0.0f);
        out[(size_t)node * 64 + lane] = (TOUT)v;
    }
}

// ---------------- launch ----------------

extern "C" void kernel_launch(void* const* d_in, const int* in_sizes, int n_in,
                              void* d_out, int out_size, void* d_ws, size_t ws_size,
                              hipStream_t stream) {
    const float* x   = (const float*)d_in[0];
    const int*   ei  = (const int*)d_in[1];
    const float* W1  = (const float*)d_in[2];
    const float* b1  = (const float*)d_in[3];
    const float* W2  = (const float*)d_in[4];
    const float* b2  = (const float*)d_in[5];
    const float* fcW = (const float*)d_in[6];
    const float* fcb = (const float*)d_in[7];
    float* out = (float*)d_out;

    const int N = in_sizes[0] / 128;
    const int E = in_sizes[1] / 2;
    const int* src = ei;
    const int* dst = ei + E;

    // ---- workspace carve (16B-aligned), peak ~40 MB ----
    auto align16 = [](size_t v) { return (v + 15) & ~(size_t)15; };
    char* p = (char*)d_ws;
    int* rowptr = (int*)p;                     p += align16(sizeof(int) * (N + 1));
    unsigned short* col = (unsigned short*)p;  p += align16(sizeof(unsigned short) * E);
    float* dinv = (float*)p;                   p += align16(sizeof(float) * N);
    int* degi = (int*)p;                       p += align16(sizeof(int) * N);
    int* cursor = (int*)p;                     p += align16(sizeof(int) * N);
    int* blocksum = (int*)p;                   p += align16(sizeof(int) * 256);
    unsigned short* W1T = (unsigned short*)p;  p += align16(2 * 128 * 128);
    unsigned short* W2T = (unsigned short*)p;  p += align16(2 * 64 * 128);
    unsigned short* fcWT = (unsigned short*)p; p += align16(2 * 64 * 64);
    unsigned short* hs1 = (unsigned short*)p;  p += align16(2 * (size_t)N * 128);  // bf16
    unsigned short* h1  = (unsigned short*)p;  p += align16(2 * (size_t)N * 128);  // bf16
    unsigned short* hs2 = (unsigned short*)p;  p += align16(2 * (size_t)N * 64);   // bf16
    unsigned short* h2  = (unsigned short*)p;  p += align16(2 * (size_t)N * 64);   // bf16

    const int B = 256;
    const int nb = (N + 255) / 256;
    const int gg = (N + 63) / 64;  // MFMA GEMM grid

    // CSR build
    k_zero_int<<<(N + B - 1) / B, B, 0, stream>>>(degi, N);
    k_count<<<(E + B - 1) / B, B, 0, stream>>>(dst, E, degi);
    k_scan1<<<nb, 256, 0, stream>>>(degi, rowptr, blocksum, N);
    k_scan2<<<1, 256, 0, stream>>>(blocksum, nb);
    k_scan3<<<nb, 256, 0, stream>>>(rowptr, blocksum, degi, cursor, dinv, N);
    k_fill<<<(E + B - 1) / B, B, 0, stream>>>(src, dst, E, cursor, col);

    // weight transpose+convert (tiny)
    k_wt<<<(128 * 128 + 255) / 256, 256, 0, stream>>>(W1, W1T, 128, 128);
    k_wt<<<(128 * 64 + 255) / 256, 256, 0, stream>>>(W2, W2T, 128, 64);
    k_wt<<<(64 * 64 + 255) / 256, 256, 0, stream>>>(fcW, fcWT, 64, 64);

    // Layer 1: 128 -> 128
    k_mgemm<128, 128, 0, float><<<gg, 256, 0, stream>>>(x, W1T, dinv, nullptr, hs1, N);
    k_agg<128, __hip_bfloat16><<<(N + 3) / 4, 256, 0, stream>>>(
        rowptr, col, hs1, dinv, b1, (__hip_bfloat16*)h1, N);

    // Layer 2: 128 -> 64
    k_mgemm<128, 64, 0, unsigned short><<<gg, 256, 0, stream>>>(h1, W2T, dinv, nullptr, hs2, N);
    k_agg<64, __hip_bfloat16><<<(N + 3) / 4, 256, 0, stream>>>(
        rowptr, col, hs2, dinv, b2, (__hip_bfloat16*)h2, N);

    // FC head: 64 -> 64, fp32 out
    k_mgemm<64, 64, 1, unsigned short><<<gg, 256, 0, stream>>>(h2, fcWT, nullptr, fcb, out, N);
}